// Round 1
// baseline (508.834 us; speedup 1.0000x reference)
//
#include <hip/hip_runtime.h>
#include <cstdint>

__device__ __forceinline__ float leaky(float v) { return v >= 0.f ? v : 0.01f * v; }

// ---------------- Encoder conv 5x5 pad2 + leaky ----------------
// One thread per (n, y, x); computes all COUT outputs, patch in registers.
template<int CIN, int COUT>
__global__ void __launch_bounds__(256) enc_conv_k(
    const float* __restrict__ src, const float* __restrict__ w,
    const float* __restrict__ bias, float* __restrict__ dst,
    int N, int H, int W)
{
    __shared__ float ws[CIN * COUT * 25];
    __shared__ float bs[COUT];
    for (int i = threadIdx.x; i < CIN * COUT * 25; i += 256) ws[i] = w[i];
    if (threadIdx.x < COUT) bs[threadIdx.x] = bias[threadIdx.x];
    __syncthreads();

    int idx = blockIdx.x * 256 + threadIdx.x;
    int total = N * H * W;
    if (idx >= total) return;
    int x = idx % W;
    int y = (idx / W) % H;
    int n = idx / (W * H);

    float acc[COUT];
#pragma unroll
    for (int co = 0; co < COUT; ++co) acc[co] = bs[co];

    for (int ci = 0; ci < CIN; ++ci) {
        const float* sp = src + ((size_t)(n * CIN + ci)) * H * W;
        float patch[25];
#pragma unroll
        for (int dy = 0; dy < 5; ++dy) {
            int iy = y + dy - 2;
            bool oky = (iy >= 0 && iy < H);
#pragma unroll
            for (int dx = 0; dx < 5; ++dx) {
                int ix = x + dx - 2;
                patch[dy * 5 + dx] = (oky && ix >= 0 && ix < W) ? sp[iy * W + ix] : 0.f;
            }
        }
#pragma unroll
        for (int co = 0; co < COUT; ++co) {
            const float* wp = &ws[(co * CIN + ci) * 25];
#pragma unroll
            for (int t = 0; t < 25; ++t)
                acc[co] = fmaf(patch[t], wp[t], acc[co]);
        }
    }
    size_t hw = (size_t)H * W;
    int pos = y * W + x;
#pragma unroll
    for (int co = 0; co < COUT; ++co)
        dst[((size_t)(n * COUT + co)) * hw + pos] = leaky(acc[co]);
}

// ---------------- 2x2 maxpool stride 2 ----------------
__global__ void __launch_bounds__(256) pool_k(
    const float* __restrict__ src, float* __restrict__ dst,
    int NC, int Ho, int Wo)
{
    int idx = blockIdx.x * 256 + threadIdx.x;
    if (idx >= NC * Ho * Wo) return;
    int x = idx % Wo;
    int y = (idx / Wo) % Ho;
    int nc = idx / (Wo * Ho);
    int Wi = 2 * Wo;
    const float* sp = src + (size_t)nc * (2 * Ho) * Wi + (2 * y) * Wi + 2 * x;
    dst[idx] = fmaxf(fmaxf(sp[0], sp[1]), fmaxf(sp[Wi], sp[Wi + 1]));
}

// ---------------- Query gather + norm (64 threads) ----------------
template<int C>
__global__ void query_k(const float* __restrict__ p1, const int* __restrict__ pts,
                        int shift, int Hp, int Wp,
                        float* __restrict__ q, float* __restrict__ nq)
{
    int t = threadIdx.x;
    if (t >= 64) return;
    int b = t >> 5;
    int py = pts[t * 2 + 0] >> shift;
    int px = pts[t * 2 + 1] >> shift;
    float s = 0.f;
#pragma unroll
    for (int c = 0; c < C; ++c) {
        float v = p1[(((size_t)(b * C + c)) * Hp + py) * Wp + px];
        q[t * C + c] = v;
        s += v * v;
    }
    nq[t] = fmaxf(sqrtf(s), 1e-8f);
}

// ---------------- Cosine-similarity attention ----------------
// grid: (ceil(P/256), B). Writes attn[(b*32+l)*P + p] (decoder layout).
template<int C>
__global__ void __launch_bounds__(256) attn_k(
    const float* __restrict__ h2p, const float* __restrict__ q,
    const float* __restrict__ nq, float* __restrict__ attn, int P)
{
    __shared__ float qs[C * 32];
    __shared__ float nqs[32];
    int b = blockIdx.y;
    for (int i = threadIdx.x; i < C * 32; i += 256) qs[i] = q[b * C * 32 + i];
    if (threadIdx.x < 32) nqs[threadIdx.x] = nq[b * 32 + threadIdx.x];
    __syncthreads();

    int p = blockIdx.x * 256 + threadIdx.x;
    if (p >= P) return;
    float v[C];
    float s = 0.f;
#pragma unroll
    for (int c = 0; c < C; ++c) {
        v[c] = h2p[((size_t)(b * C + c)) * P + p];
        s += v[c] * v[c];
    }
    float inv_n2 = 1.f / fmaxf(sqrtf(s), 1e-8f);
    for (int l = 0; l < 32; ++l) {
        float d = 0.f;
#pragma unroll
        for (int c = 0; c < C; ++c) d = fmaf(v[c], qs[l * C + c], d);
        attn[((size_t)(b * 32 + l)) * P + p] = d * inv_n2 / nqs[l];
    }
}

// ---------------- Decoder conv 3x3 pad1, fused upsample+concat ----------------
// Virtual input channels = [prev(CP) upsampled, attn(1) upsampled, feat(CF)].
// prev at R/2 (index iy>>1), attn at R/2 (per-k), feat at R (image k&1).
template<int CP, int CF, int COUT, bool TILEDPREV, bool DOLEAKY>
__global__ void __launch_bounds__(256) dec_conv_k(
    const float* __restrict__ prev, const float* __restrict__ attn,
    const float* __restrict__ feat, const float* __restrict__ w,
    const float* __restrict__ bias, float* __restrict__ out, int R)
{
    constexpr int CIN = CP + 1 + CF;
    __shared__ float ws[COUT * CIN * 9];
    __shared__ float bs[COUT];
    for (int i = threadIdx.x; i < COUT * CIN * 9; i += 256) ws[i] = w[i];
    if (threadIdx.x < COUT) bs[threadIdx.x] = bias[threadIdx.x];
    __syncthreads();

    int idx = blockIdx.x * 256 + threadIdx.x;
    int total = 64 * R * R;
    if (idx >= total) return;
    int x = idx % R;
    int y = (idx / R) % R;
    int k = idx / (R * R);
    int kprev = TILEDPREV ? (k & 1) : k;
    int kf = k & 1;
    int Rh = R >> 1;

    float acc[COUT];
#pragma unroll
    for (int co = 0; co < COUT; ++co) acc[co] = bs[co];

#pragma unroll
    for (int dy = 0; dy < 3; ++dy) {
        int iy = y + dy - 1;
        if (iy < 0 || iy >= R) continue;
        int py = iy >> 1;
#pragma unroll
        for (int dx = 0; dx < 3; ++dx) {
            int ix = x + dx - 1;
            if (ix < 0 || ix >= R) continue;
            int px = ix >> 1;
            int tap = dy * 3 + dx;
#pragma unroll
            for (int ci = 0; ci < CP; ++ci) {
                float v = prev[(((size_t)(kprev * CP + ci)) * Rh + py) * Rh + px];
#pragma unroll
                for (int co = 0; co < COUT; ++co)
                    acc[co] = fmaf(ws[(co * CIN + ci) * 9 + tap], v, acc[co]);
            }
            {
                float v = attn[((size_t)k * Rh + py) * Rh + px];
#pragma unroll
                for (int co = 0; co < COUT; ++co)
                    acc[co] = fmaf(ws[(co * CIN + CP) * 9 + tap], v, acc[co]);
            }
#pragma unroll
            for (int cf = 0; cf < CF; ++cf) {
                float v = feat[(((size_t)(kf * CF + cf)) * R + iy) * R + ix];
#pragma unroll
                for (int co = 0; co < COUT; ++co)
                    acc[co] = fmaf(ws[(co * CIN + CP + 1 + cf) * 9 + tap], v, acc[co]);
            }
        }
    }
    size_t rr = (size_t)R * R;
    int pos = y * R + x;
#pragma unroll
    for (int co = 0; co < COUT; ++co) {
        float v = acc[co];
        out[((size_t)(k * COUT + co)) * rr + pos] = DOLEAKY ? leaky(v) : v;
    }
}

extern "C" void kernel_launch(void* const* d_in, const int* in_sizes, int n_in,
                              void* d_out, int out_size, void* d_ws, size_t ws_size,
                              hipStream_t stream)
{
    (void)in_sizes; (void)n_in; (void)out_size; (void)ws_size;
    const float* x1 = (const float*)d_in[0];
    const float* x2 = (const float*)d_in[1];
    const int* pts = (const int*)d_in[2];
    const float* ew[4] = {(const float*)d_in[3], (const float*)d_in[5],
                          (const float*)d_in[7], (const float*)d_in[9]};
    const float* eb[4] = {(const float*)d_in[4], (const float*)d_in[6],
                          (const float*)d_in[8], (const float*)d_in[10]};
    const float* dw[4] = {(const float*)d_in[11], (const float*)d_in[13],
                          (const float*)d_in[15], (const float*)d_in[17]};
    const float* db[4] = {(const float*)d_in[12], (const float*)d_in[14],
                          (const float*)d_in[16], (const float*)d_in[18]};

    float* wsp = (float*)d_ws;
    size_t off = 0;
    auto A = [&](size_t n) { float* p = wsp + off; off += n; return p; };

    const int CH[5] = {3, 4, 8, 16, 16};
    float *c1[4], *c2[4], *p1[4], *p2[4];
    for (int i = 0; i < 4; ++i) {
        int R = 256 >> i, Rp = R >> 1, C = CH[i + 1];
        c1[i] = A((size_t)2 * C * R * R);
        c2[i] = A((size_t)2 * C * R * R);
        p1[i] = A((size_t)2 * C * Rp * Rp);
        p2[i] = A((size_t)2 * C * Rp * Rp);
    }
    float *q[4], *nq[4], *at[4];
    for (int i = 0; i < 4; ++i) {
        int C = CH[i + 1], Rp = 128 >> i;
        q[i] = A((size_t)64 * C);
        nq[i] = A(64);
        at[i] = A((size_t)64 * Rp * Rp);
    }
    float* dec0 = A((size_t)64 * 16 * 32 * 32);
    float* dec1 = A((size_t)64 * 8 * 64 * 64);
    float* dec2 = A((size_t)64 * 4 * 128 * 128);
    float* outp = (float*)d_out;

    // ---- Encoder level 0: 3 -> 4, 256 -> pool 128
    {
        int R = 256, Rp = 128;
        int nb = (2 * R * R + 255) / 256;
        enc_conv_k<3, 4><<<nb, 256, 0, stream>>>(x1, ew[0], eb[0], c1[0], 2, R, R);
        enc_conv_k<3, 4><<<nb, 256, 0, stream>>>(x2, ew[0], eb[0], c2[0], 2, R, R);
        int pt = 2 * 4 * Rp * Rp;
        pool_k<<<(pt + 255) / 256, 256, 0, stream>>>(c1[0], p1[0], 2 * 4, Rp, Rp);
        pool_k<<<(pt + 255) / 256, 256, 0, stream>>>(c2[0], p2[0], 2 * 4, Rp, Rp);
        query_k<4><<<1, 64, 0, stream>>>(p1[0], pts, 1, Rp, Rp, q[0], nq[0]);
        dim3 g((Rp * Rp + 255) / 256, 2);
        attn_k<4><<<g, 256, 0, stream>>>(p2[0], q[0], nq[0], at[0], Rp * Rp);
    }
    // ---- Encoder level 1: 4 -> 8, 128 -> pool 64
    {
        int R = 128, Rp = 64;
        int nb = (2 * R * R + 255) / 256;
        enc_conv_k<4, 8><<<nb, 256, 0, stream>>>(p1[0], ew[1], eb[1], c1[1], 2, R, R);
        enc_conv_k<4, 8><<<nb, 256, 0, stream>>>(p2[0], ew[1], eb[1], c2[1], 2, R, R);
        int pt = 2 * 8 * Rp * Rp;
        pool_k<<<(pt + 255) / 256, 256, 0, stream>>>(c1[1], p1[1], 2 * 8, Rp, Rp);
        pool_k<<<(pt + 255) / 256, 256, 0, stream>>>(c2[1], p2[1], 2 * 8, Rp, Rp);
        query_k<8><<<1, 64, 0, stream>>>(p1[1], pts, 2, Rp, Rp, q[1], nq[1]);
        dim3 g((Rp * Rp + 255) / 256, 2);
        attn_k<8><<<g, 256, 0, stream>>>(p2[1], q[1], nq[1], at[1], Rp * Rp);
    }
    // ---- Encoder level 2: 8 -> 16, 64 -> pool 32
    {
        int R = 64, Rp = 32;
        int nb = (2 * R * R + 255) / 256;
        enc_conv_k<8, 16><<<nb, 256, 0, stream>>>(p1[1], ew[2], eb[2], c1[2], 2, R, R);
        enc_conv_k<8, 16><<<nb, 256, 0, stream>>>(p2[1], ew[2], eb[2], c2[2], 2, R, R);
        int pt = 2 * 16 * Rp * Rp;
        pool_k<<<(pt + 255) / 256, 256, 0, stream>>>(c1[2], p1[2], 2 * 16, Rp, Rp);
        pool_k<<<(pt + 255) / 256, 256, 0, stream>>>(c2[2], p2[2], 2 * 16, Rp, Rp);
        query_k<16><<<1, 64, 0, stream>>>(p1[2], pts, 3, Rp, Rp, q[2], nq[2]);
        dim3 g((Rp * Rp + 255) / 256, 2);
        attn_k<16><<<g, 256, 0, stream>>>(p2[2], q[2], nq[2], at[2], Rp * Rp);
    }
    // ---- Encoder level 3: 16 -> 16, 32 -> pool 16
    {
        int R = 32, Rp = 16;
        int nb = (2 * R * R + 255) / 256;
        enc_conv_k<16, 16><<<nb, 256, 0, stream>>>(p1[2], ew[3], eb[3], c1[3], 2, R, R);
        enc_conv_k<16, 16><<<nb, 256, 0, stream>>>(p2[2], ew[3], eb[3], c2[3], 2, R, R);
        int pt = 2 * 16 * Rp * Rp;
        pool_k<<<(pt + 255) / 256, 256, 0, stream>>>(c1[3], p1[3], 2 * 16, Rp, Rp);
        pool_k<<<(pt + 255) / 256, 256, 0, stream>>>(c2[3], p2[3], 2 * 16, Rp, Rp);
        query_k<16><<<1, 64, 0, stream>>>(p1[3], pts, 4, Rp, Rp, q[3], nq[3]);
        dim3 g((Rp * Rp + 255) / 256, 2);
        attn_k<16><<<g, 256, 0, stream>>>(p2[3], q[3], nq[3], at[3], Rp * Rp);
    }

    // ---- Decoder (virtual batch 64; fused upsample + concat) ----
    // dec0: in [p2[3](16) + at[3](1)]@16 up-> 32, + c2[3](16)@32 -> 16 ch, leaky
    {
        int R = 32, tot = 64 * R * R;
        dec_conv_k<16, 16, 16, true, true><<<(tot + 255) / 256, 256, 0, stream>>>(
            p2[3], at[3], c2[3], dw[0], db[0], dec0, R);
    }
    // dec1: [dec0(16) + at[2](1)]@32 up-> 64, + c2[2](16)@64 -> 8 ch, leaky
    {
        int R = 64, tot = 64 * R * R;
        dec_conv_k<16, 16, 8, false, true><<<(tot + 255) / 256, 256, 0, stream>>>(
            dec0, at[2], c2[2], dw[1], db[1], dec1, R);
    }
    // dec2: [dec1(8) + at[1](1)]@64 up-> 128, + c2[1](8)@128 -> 4 ch, leaky
    {
        int R = 128, tot = 64 * R * R;
        dec_conv_k<8, 8, 4, false, true><<<(tot + 255) / 256, 256, 0, stream>>>(
            dec1, at[1], c2[1], dw[2], db[2], dec2, R);
    }
    // dec3: [dec2(4) + at[0](1)]@128 up-> 256, + c2[0](4)@256 -> 1 ch, NO leaky
    {
        int R = 256, tot = 64 * R * R;
        dec_conv_k<4, 4, 1, false, false><<<(tot + 255) / 256, 256, 0, stream>>>(
            dec2, at[0], c2[0], dw[3], db[3], outp, R);
    }
}

// Round 2
// 204.923 us; speedup vs baseline: 2.4830x; 2.4830x over previous
//
#include <hip/hip_runtime.h>
#include <cstdint>

__device__ __forceinline__ float leaky(float v) { return v >= 0.f ? v : 0.01f * v; }

// ================= Encoder: conv5x5 pad2 + leaky + fused 2x2 maxpool =================
// Thread handles an x-pair (2*col, 2*col+1) at row y of virtual image n (0,1 = x1 batches;
// 2,3 = x2 batches) for output-channel group g. Writes pre-pool conv (image-2 only, c2)
// and pooled output for all images (pout), via LDS exchange of vertical neighbor rows.
template<int R, int CI, int CO, int COG>
__global__ void __launch_bounds__(256) enc_k(
    const float* __restrict__ src1, const float* __restrict__ src2,
    const float* __restrict__ w, const float* __restrict__ bias,
    float* __restrict__ c2, float* __restrict__ pout)
{
    constexpr int W = R, H = R, Wt = R / 2;
    constexpr int RPB = 256 / Wt;              // rows per block (even)
    __shared__ float ws[COG * CI * 25];
    __shared__ float pl[(RPB / 2) * COG * Wt];

    int t = threadIdx.x;
    int gid = blockIdx.x * 256 + t;
    int col = gid % Wt;
    int y = (gid / Wt) % H;
    int n = (gid / (Wt * H)) & 3;
    int g = gid / (Wt * H * 4);

    for (int i = t; i < COG * CI * 25; i += 256) ws[i] = w[g * COG * CI * 25 + i];
    __syncthreads();

    const float* sp = (n < 2) ? (src1 + (size_t)n * CI * H * W)
                              : (src2 + (size_t)(n - 2) * CI * H * W);
    int x0 = col * 2;

    float acc[COG][2];
#pragma unroll
    for (int cg = 0; cg < COG; ++cg) { float b0 = bias[g * COG + cg]; acc[cg][0] = b0; acc[cg][1] = b0; }

    bool okr[5], okc[3];
#pragma unroll
    for (int i = 0; i < 5; ++i) { int yy = y + i - 2; okr[i] = (yy >= 0) && (yy < H); }
#pragma unroll
    for (int j = 0; j < 3; ++j) { int xx = x0 + 2 * j - 2; okc[j] = (xx >= 0) && (xx < W); }

    for (int ci = 0; ci < CI; ++ci) {
        const float* s = sp + ci * H * W + (y - 2) * W + (x0 - 2);
        float p[5][6];
#pragma unroll
        for (int i = 0; i < 5; ++i) {
#pragma unroll
            for (int j = 0; j < 3; ++j) {
                if (okr[i] & okc[j]) {
                    float2 v = *(const float2*)(s + i * W + 2 * j);
                    p[i][2 * j] = v.x; p[i][2 * j + 1] = v.y;
                } else { p[i][2 * j] = 0.f; p[i][2 * j + 1] = 0.f; }
            }
        }
#pragma unroll
        for (int cg = 0; cg < COG; ++cg) {
#pragma unroll
            for (int dy = 0; dy < 5; ++dy) {
#pragma unroll
                for (int dx = 0; dx < 5; ++dx) {
                    float wv = ws[(cg * CI + ci) * 25 + dy * 5 + dx];
                    acc[cg][0] = fmaf(wv, p[dy][dx],     acc[cg][0]);
                    acc[cg][1] = fmaf(wv, p[dy][dx + 1], acc[cg][1]);
                }
            }
        }
    }

    int r = t / Wt;
    float m[COG];
#pragma unroll
    for (int cg = 0; cg < COG; ++cg) {
        float v0 = leaky(acc[cg][0]), v1 = leaky(acc[cg][1]);
        m[cg] = fmaxf(v0, v1);
        if (n >= 2) {
            float2 stv; stv.x = v0; stv.y = v1;
            *(float2*)(c2 + ((size_t)((n - 2) * CO + g * COG + cg)) * H * W + y * W + x0) = stv;
        }
    }
    if (r & 1) {
#pragma unroll
        for (int cg = 0; cg < COG; ++cg)
            pl[((r >> 1) * COG + cg) * Wt + col] = m[cg];
    }
    __syncthreads();
    if (!(r & 1)) {
#pragma unroll
        for (int cg = 0; cg < COG; ++cg) {
            float pv = fmaxf(m[cg], pl[((r >> 1) * COG + cg) * Wt + col]);
            pout[((size_t)(n * CO + g * COG + cg)) * Wt * Wt + (y >> 1) * Wt + col] = pv;
        }
    }
}

// ================= Attention: fused query gather + cosine similarity =================
// pool layout [4][C][RP][RP]; n=b is image-1 (queries), n=2+b image-2 (keys).
// Writes out[(b*32+l)*P + p].
template<int C, int RP, int SHIFT>
__global__ void __launch_bounds__(256) attn_k(
    const float* __restrict__ pool, const int* __restrict__ pts,
    float* __restrict__ out)
{
    constexpr int P = RP * RP;
    __shared__ float qs[32 * C];
    int t = threadIdx.x, b = blockIdx.y;
    if (t < 32) {
        int l = t;
        int py = pts[(b * 32 + l) * 2 + 0] >> SHIFT;
        int px = pts[(b * 32 + l) * 2 + 1] >> SHIFT;
        const float* qp = pool + (size_t)(b * C) * P + py * RP + px;
        float v[C]; float s = 0.f;
#pragma unroll
        for (int c = 0; c < C; ++c) { v[c] = qp[c * P]; s += v[c] * v[c]; }
        float invn = 1.f / fmaxf(sqrtf(s), 1e-8f);
#pragma unroll
        for (int c = 0; c < C; ++c) qs[l * C + c] = v[c] * invn;
    }
    __syncthreads();
    int p = blockIdx.x * 256 + t;
    const float* hp = pool + (size_t)((2 + b) * C) * P + p;
    float v[C]; float s = 0.f;
#pragma unroll
    for (int c = 0; c < C; ++c) { v[c] = hp[c * P]; s += v[c] * v[c]; }
    float invn2 = 1.f / fmaxf(sqrtf(s), 1e-8f);
#pragma unroll 4
    for (int l = 0; l < 32; ++l) {
        float d = 0.f;
#pragma unroll
        for (int c = 0; c < C; ++c) d = fmaf(v[c], qs[l * C + c], d);
        out[(size_t)(b * 32 + l) * P + p] = d * invn2;
    }
}

// ================= Decoder conv3x3 pad1, fused upsample+concat, 2x2 output tile ======
// Thread computes out[k][co..co+COG][2ty..2ty+1][2tx..2tx+1].
// Half-res inputs (prev CP ch + attn) need only a 3x3 patch; full-res feat a 4x4 patch.
template<int R, int CP, int CF, int CO, int COG, bool TILEDPREV, bool DOLEAKY>
__global__ void __launch_bounds__(256) dec_k(
    const float* __restrict__ prev, const float* __restrict__ attn,
    const float* __restrict__ feat, const float* __restrict__ w,
    const float* __restrict__ bias, float* __restrict__ out)
{
    constexpr int CIN = CP + 1 + CF, Rh = R / 2;
    __shared__ float ws[COG * CIN * 9];
    int t = threadIdx.x, gid = blockIdx.x * 256 + t;
    int tx = gid % Rh;
    int ty = (gid / Rh) % Rh;
    int k = (gid / (Rh * Rh)) & 63;
    int g = gid / (Rh * Rh * 64);

    for (int i = t; i < COG * CIN * 9; i += 256) ws[i] = w[g * COG * CIN * 9 + i];
    __syncthreads();

    float acc[COG][2][2];
#pragma unroll
    for (int cg = 0; cg < COG; ++cg) {
        float b0 = bias[g * COG + cg];
        acc[cg][0][0] = b0; acc[cg][0][1] = b0; acc[cg][1][0] = b0; acc[cg][1][1] = b0;
    }

    bool hr[3], hc[3], fr[4], fc[4];
#pragma unroll
    for (int i = 0; i < 3; ++i) {
        int yy = ty - 1 + i; hr[i] = (yy >= 0) && (yy < Rh);
        int xx = tx - 1 + i; hc[i] = (xx >= 0) && (xx < Rh);
    }
#pragma unroll
    for (int i = 0; i < 4; ++i) {
        int yy = 2 * ty - 1 + i; fr[i] = (yy >= 0) && (yy < R);
        int xx = 2 * tx - 1 + i; fc[i] = (xx >= 0) && (xx < R);
    }

    // half-res patch row/col index for output subpixel s and tap d: HM<s>[d]
    constexpr int HM0[3] = {0, 1, 1};
    constexpr int HM1[3] = {1, 1, 2};

    int np = TILEDPREV ? (2 + (k & 1)) : k;
    int kf = k & 1;

    for (int ci = 0; ci < CP + 1; ++ci) {   // prev channels, then attn at ci==CP
        const float* bp = (ci < CP) ? (prev + ((size_t)(np * CP + ci)) * Rh * Rh)
                                    : (attn + (size_t)k * Rh * Rh);
        bp += (ty - 1) * Rh + (tx - 1);
        float P[3][3];
#pragma unroll
        for (int i = 0; i < 3; ++i)
#pragma unroll
            for (int j = 0; j < 3; ++j)
                P[i][j] = (hr[i] & hc[j]) ? bp[i * Rh + j] : 0.f;
#pragma unroll
        for (int cg = 0; cg < COG; ++cg) {
#pragma unroll
            for (int dy = 0; dy < 3; ++dy) {
#pragma unroll
                for (int dx = 0; dx < 3; ++dx) {
                    float wv = ws[(cg * CIN + ci) * 9 + dy * 3 + dx];
                    acc[cg][0][0] = fmaf(wv, P[HM0[dy]][HM0[dx]], acc[cg][0][0]);
                    acc[cg][0][1] = fmaf(wv, P[HM0[dy]][HM1[dx]], acc[cg][0][1]);
                    acc[cg][1][0] = fmaf(wv, P[HM1[dy]][HM0[dx]], acc[cg][1][0]);
                    acc[cg][1][1] = fmaf(wv, P[HM1[dy]][HM1[dx]], acc[cg][1][1]);
                }
            }
        }
    }

    for (int cf = 0; cf < CF; ++cf) {
        const float* bp = feat + ((size_t)(kf * CF + cf)) * R * R + (2 * ty - 1) * R + (2 * tx - 1);
        float F[4][4];
#pragma unroll
        for (int i = 0; i < 4; ++i)
#pragma unroll
            for (int j = 0; j < 4; ++j)
                F[i][j] = (fr[i] & fc[j]) ? bp[i * R + j] : 0.f;
#pragma unroll
        for (int cg = 0; cg < COG; ++cg) {
#pragma unroll
            for (int dy = 0; dy < 3; ++dy) {
#pragma unroll
                for (int dx = 0; dx < 3; ++dx) {
                    float wv = ws[(cg * CIN + CP + 1 + cf) * 9 + dy * 3 + dx];
                    acc[cg][0][0] = fmaf(wv, F[dy][dx],         acc[cg][0][0]);
                    acc[cg][0][1] = fmaf(wv, F[dy][dx + 1],     acc[cg][0][1]);
                    acc[cg][1][0] = fmaf(wv, F[dy + 1][dx],     acc[cg][1][0]);
                    acc[cg][1][1] = fmaf(wv, F[dy + 1][dx + 1], acc[cg][1][1]);
                }
            }
        }
    }

#pragma unroll
    for (int cg = 0; cg < COG; ++cg) {
        float v00 = acc[cg][0][0], v01 = acc[cg][0][1];
        float v10 = acc[cg][1][0], v11 = acc[cg][1][1];
        if (DOLEAKY) { v00 = leaky(v00); v01 = leaky(v01); v10 = leaky(v10); v11 = leaky(v11); }
        float* op = out + ((size_t)(k * CO + g * COG + cg)) * R * R + (2 * ty) * R + 2 * tx;
        float2 a; a.x = v00; a.y = v01; *(float2*)op = a;
        float2 b2; b2.x = v10; b2.y = v11; *(float2*)(op + R) = b2;
    }
}

extern "C" void kernel_launch(void* const* d_in, const int* in_sizes, int n_in,
                              void* d_out, int out_size, void* d_ws, size_t ws_size,
                              hipStream_t stream)
{
    (void)in_sizes; (void)n_in; (void)out_size; (void)ws_size;
    const float* x1 = (const float*)d_in[0];
    const float* x2 = (const float*)d_in[1];
    const int* pts = (const int*)d_in[2];
    const float* ew[4] = {(const float*)d_in[3], (const float*)d_in[5],
                          (const float*)d_in[7], (const float*)d_in[9]};
    const float* eb[4] = {(const float*)d_in[4], (const float*)d_in[6],
                          (const float*)d_in[8], (const float*)d_in[10]};
    const float* dw[4] = {(const float*)d_in[11], (const float*)d_in[13],
                          (const float*)d_in[15], (const float*)d_in[17]};
    const float* db[4] = {(const float*)d_in[12], (const float*)d_in[14],
                          (const float*)d_in[16], (const float*)d_in[18]};

    float* wsp = (float*)d_ws;
    size_t off = 0;
    auto A = [&](size_t n) { float* p = wsp + off; off += n; return p; };

    // pooled activations, all 4 virtual images: [4][C][Rp][Rp]
    float* p0 = A((size_t)4 * 4 * 128 * 128);
    float* p1 = A((size_t)4 * 8 * 64 * 64);
    float* p2 = A((size_t)4 * 16 * 32 * 32);
    float* p3 = A((size_t)4 * 16 * 16 * 16);
    // pre-pool conv outputs, image-2 only: [2][C][R][R]
    float* c2_0 = A((size_t)2 * 4 * 256 * 256);
    float* c2_1 = A((size_t)2 * 8 * 128 * 128);
    float* c2_2 = A((size_t)2 * 16 * 64 * 64);
    float* c2_3 = A((size_t)2 * 16 * 32 * 32);
    // attention maps [64][Rp][Rp]
    float* at0 = A((size_t)64 * 128 * 128);
    float* at1 = A((size_t)64 * 64 * 64);
    float* at2 = A((size_t)64 * 32 * 32);
    float* at3 = A((size_t)64 * 16 * 16);
    // decoder intermediates
    float* dec0 = A((size_t)64 * 16 * 32 * 32);
    float* dec1 = A((size_t)64 * 8 * 64 * 64);
    float* dec2 = A((size_t)64 * 4 * 128 * 128);
    float* outp = (float*)d_out;

    // ---- Encoder (4 virtual images per launch, conv+leaky+pool fused) ----
    enc_k<256, 3, 4, 2><<<1024, 256, 0, stream>>>(x1, x2, ew[0], eb[0], c2_0, p0);
    enc_k<128, 4, 8, 2><<<512, 256, 0, stream>>>(p0, p0 + (size_t)2 * 4 * 128 * 128,
                                                 ew[1], eb[1], c2_1, p1);
    enc_k<64, 8, 16, 2><<<256, 256, 0, stream>>>(p1, p1 + (size_t)2 * 8 * 64 * 64,
                                                 ew[2], eb[2], c2_2, p2);
    enc_k<32, 16, 16, 1><<<128, 256, 0, stream>>>(p2, p2 + (size_t)2 * 16 * 32 * 32,
                                                  ew[3], eb[3], c2_3, p3);

    // ---- Attention (query gather fused) ----
    { dim3 g(64, 2); attn_k<4, 128, 1><<<g, 256, 0, stream>>>(p0, pts, at0); }
    { dim3 g(16, 2); attn_k<8, 64, 2><<<g, 256, 0, stream>>>(p1, pts, at1); }
    { dim3 g(4, 2);  attn_k<16, 32, 3><<<g, 256, 0, stream>>>(p2, pts, at2); }
    { dim3 g(1, 2);  attn_k<16, 16, 4><<<g, 256, 0, stream>>>(p3, pts, at3); }

    // ---- Decoder (fused upsample+concat, 2x2 tiles) ----
    dec_k<32, 16, 16, 16, 2, true, true><<<512, 256, 0, stream>>>(p3, at3, c2_3, dw[0], db[0], dec0);
    dec_k<64, 16, 16, 8, 2, false, true><<<1024, 256, 0, stream>>>(dec0, at2, c2_2, dw[1], db[1], dec1);
    dec_k<128, 8, 8, 4, 4, false, true><<<1024, 256, 0, stream>>>(dec1, at1, c2_1, dw[2], db[2], dec2);
    dec_k<256, 4, 4, 1, 1, false, false><<<4096, 256, 0, stream>>>(dec2, at0, c2_0, dw[3], db[3], outp);
}